// Round 5
// baseline (341.555 us; speedup 1.0000x reference)
//
#include <hip/hip_runtime.h>

// DepthDeformConvPack on MI355X — round 5: latency hiding.
// r4 post-mortem: K3 grid-limited at 1 block/CU (22% occupancy), MfmaUtil 6%,
// VALU 21% — everything idle waiting on L2 gathers. Changes:
//   K3: (a) 512 blocks (co split in halves, BM=128) -> 2 blocks/CU;
//       (b) tap-major K (k=tap*256+c): tap = ic>>2 is block-uniform, so
//           bilinear params live in registers (reloaded once per 4 chunks) —
//           no per-sample LDS reads. Safe now because the XCD swizzle keeps
//           each XCD's strip+halo (~2.6 MB) inside its 4 MB L2 (r3's 775 MB
//           refetch had no swizzle).
//   K1: 8 waves/block (10 ch/wave) -> 32 waves/CU.
//   K2: sampling params computed once per block into LDS + paired row loads.

typedef __bf16 bf16x8 __attribute__((ext_vector_type(8)));
typedef float f32x4 __attribute__((ext_vector_type(4)));
typedef float float2_u __attribute__((ext_vector_type(2), aligned(4)));

__device__ __forceinline__ unsigned short f2bf(float f) {
  unsigned b = __float_as_uint(f);
  return (unsigned short)((b + 0x7fffu + ((b >> 16) & 1u)) >> 16);
}

// ---------------------------------------------------------------------------
// K0: weight[co][c][tap] fp32 -> wbf[co][tap*256 + c] bf16 (tap-major)
// ---------------------------------------------------------------------------
__global__ __launch_bounds__(256) void k_prep_weight(
    const float* __restrict__ w, unsigned short* __restrict__ wbf)
{
  const int tap = blockIdx.x;   // 0..8
  const int co  = blockIdx.y;   // 0..255
  const int c   = threadIdx.x;  // 0..255
  wbf[co * 2304 + tap * 256 + c] = f2bf(w[(co * 256 + c) * 9 + tap]);
}

// ---------------------------------------------------------------------------
// K1: offset conv. grid = 4 ch-segments x (n,ho)=256 -> 1024 blocks,
// 512 threads = 8 waves, wave handles 10 channels of its 80-ch segment.
// ---------------------------------------------------------------------------
__global__ __launch_bounds__(512) void k_offset_conv(
    const float* __restrict__ x, const float* __restrict__ depth,
    const float* __restrict__ off_w, const float* __restrict__ off_b,
    float* __restrict__ offs)
{
  const int seg = blockIdx.x >> 8;        // 0..3
  const int nh  = blockIdx.x & 255;
  const int n = nh >> 6, ho = nh & 63;
  const int tid = threadIdx.x;
  const int lane = tid & 63;              // == wo
  const int wave = tid >> 6;              // 0..7

  float acc[18];
#pragma unroll
  for (int i = 0; i < 18; ++i) acc[i] = 0.f;

  const int c0 = __builtin_amdgcn_readfirstlane(seg * 80 + wave * 10);

  for (int ci = 0; ci < 10; ++ci) {
    const int c = c0 + ci;
    const float* p = (c < 256) ? (x + (((n << 8) + c) << 12))
                               : (depth + (((n << 6) + (c - 256)) << 12));
    const float v0 = (ho > 0)  ? p[((ho - 1) << 6) + lane] : 0.f;
    const float v1 =             p[( ho      << 6) + lane];
    const float v2 = (ho < 63) ? p[((ho + 1) << 6) + lane] : 0.f;

    float v[9];
#pragma unroll
    for (int ky = 0; ky < 3; ++ky) {
      const float r = (ky == 0) ? v0 : ((ky == 1) ? v1 : v2);
#pragma unroll
      for (int kx = 0; kx < 3; ++kx) {
        const int src = lane + kx - 1;
        const float s = __shfl(r, src & 63);
        v[ky * 3 + kx] = (src >= 0 && src < 64) ? s : 0.f;
      }
    }
    const float* wp = off_w + c * 9;   // wave-uniform address
#pragma unroll
    for (int co = 0; co < 18; ++co) {
      const float* w = wp + co * 2880;
#pragma unroll
      for (int t = 0; t < 9; ++t) acc[co] += v[t] * w[t];
    }
  }

  __shared__ float red[8][18][64];
#pragma unroll
  for (int co = 0; co < 18; ++co) red[wave][co][lane] = acc[co];
  __syncthreads();
  for (int o = tid; o < 18 * 64; o += 512) {
    const int co = o >> 6, wo = o & 63;
    float s = 0.f;
#pragma unroll
    for (int w = 0; w < 8; ++w) s += red[w][co][wo];
    if (seg == 0) s += off_b[co];
    atomicAdd(&offs[((n * 18 + co) << 12) + (ho << 6) + wo], s);
  }
}

// ---------------------------------------------------------------------------
// K2: mask deform conv on depth + sigmoid. 256 blocks (n,ho), 512 thr = 8 waves.
// Phase 0 builds per-(tap,px) paired-load params in LDS once per block.
// ---------------------------------------------------------------------------
__global__ __launch_bounds__(512) void k_mask_conv(
    const float* __restrict__ depth, const float* __restrict__ offs,
    const float* __restrict__ mask_w, const float* __restrict__ mask_b,
    float* __restrict__ mask)
{
  __shared__ float4 qw[9][64];
  __shared__ int2   qi[9][64];
  __shared__ float  red[8][9][64];

  const int n  = blockIdx.x >> 6;
  const int ho = blockIdx.x & 63;
  const int tid  = threadIdx.x;
  const int lane = tid & 63;          // wo
  const int wave = tid >> 6;          // 0..7

  for (int e = tid; e < 576; e += 512) {
    const int tap = e >> 6, pl = e & 63;
    const float dy = offs[((n * 18 + 2 * tap) << 12) + (ho << 6) + pl];
    const float dx = offs[((n * 18 + 2 * tap + 1) << 12) + (ho << 6) + pl];
    const float yy = (float)(ho - 1 + tap / 3) + dy;
    const float xx = (float)(pl - 1 + tap % 3) + dx;
    const float y0f = floorf(yy), x0f = floorf(xx);
    const float ly = yy - y0f, lx = xx - x0f;
    const int y0 = (int)y0f, x0 = (int)x0f;
    const int y0c = min(max(y0, 0), 63);
    const int y1c = min(max(y0 + 1, 0), 63);
    const float fy0 = (y0 >= 0 && y0 < 64) ? 1.f : 0.f;
    const float fy1 = (y0 >= -1 && y0 < 63) ? 1.f : 0.f;
    const int x0c = min(max(x0, 0), 63);
    const int x1c = min(max(x0 + 1, 0), 63);
    const int bx  = min(max(x0, 0), 62);
    const float vx0 = (x0 >= 0 && x0 < 64) ? 1.f : 0.f;
    const float vx1 = (x0 >= -1 && x0 < 63) ? 1.f : 0.f;
    const float wl = (1.f - lx) * vx0 * ((x0c == bx) ? 1.f : 0.f)
                   + lx * vx1 * ((x1c == bx) ? 1.f : 0.f);
    const float wr = (1.f - lx) * vx0 * ((x0c == bx + 1) ? 1.f : 0.f)
                   + lx * vx1 * ((x1c == bx + 1) ? 1.f : 0.f);
    const float a0 = (1.f - ly) * fy0;
    const float a1 = ly * fy1;
    qw[tap][pl] = make_float4(wl * a0, wr * a0, wl * a1, wr * a1);
    qi[tap][pl] = make_int2((((y0c << 6) + bx) << 2), (((y1c << 6) + bx) << 2));
  }
  __syncthreads();

  float acc[9];
#pragma unroll
  for (int i = 0; i < 9; ++i) acc[i] = 0.f;

  const int cbase = __builtin_amdgcn_readfirstlane(wave * 8);
  for (int cc = 0; cc < 8; ++cc) {
    const int c = cbase + cc;
    const char* p = (const char*)(depth + (((n << 6) + c) << 12));
    const float* wp = mask_w + c * 9;   // wave-uniform
#pragma unroll
    for (int tap = 0; tap < 9; ++tap) {
      const float4 w4 = qw[tap][lane];
      const int2 ii   = qi[tap][lane];
      const float2_u pa = *(const float2_u*)(p + ii.x);
      const float2_u pb = *(const float2_u*)(p + ii.y);
      const float val = pa.x * w4.x + pa.y * w4.y + pb.x * w4.z + pb.y * w4.w;
#pragma unroll
      for (int co = 0; co < 9; ++co) acc[co] += val * wp[co * 576 + tap];
    }
  }

#pragma unroll
  for (int co = 0; co < 9; ++co) red[wave][co][lane] = acc[co];
  __syncthreads();
  for (int o = tid; o < 9 * 64; o += 512) {
    const int co = o >> 6, w2 = o & 63;
    float s = mask_b[co];
#pragma unroll
    for (int w = 0; w < 8; ++w) s += red[w][co][w2];
    mask[((n * 9 + co) << 12) + (ho << 6) + w2] = 1.f / (1.f + expf(-s));
  }
}

// ---------------------------------------------------------------------------
// K3: main modulated deform conv, bf16 MFMA GEMM, tap-major K.
// C[256co x 16384px] = Wbf[256 x 2304] * cols[2304 x px], k = tap*256 + c.
// Grid 512: b&7 = XCD strip (32 rows of one batch), slot&1 = co half.
// Block: BM=128, BN=64 px, BK=64, 512 threads = 8 waves; wave = 16 co.
// Chunk ic: tap = ic>>2 (block-uniform) -> params in registers, reloaded
// from LDS once per 4 chunks. Channels per chunk: 64*(ic&3) + oct*8 + j.
// ---------------------------------------------------------------------------
__global__ __launch_bounds__(512, 2) void k_deform_gemm(
    const float* __restrict__ x, const float* __restrict__ offs,
    const float* __restrict__ mask, const unsigned short* __restrict__ wbf,
    const float* __restrict__ bias, float* __restrict__ out)
{
  __shared__ __align__(16) unsigned short Bs[2][64][72];  // 18432 B
  __shared__ float4 pwT[9][64];   // [tap][px] remapped weights  9216 B
  __shared__ int2   piT[9][64];   // [tap][px] byte offsets      4608 B

  const int tid = threadIdx.x;
  const int b    = blockIdx.x;                    // 0..511
  const int xcd  = b & 7;
  const int slot = b >> 3;                        // 0..63
  const int coh  = slot & 1;
  const int rs   = slot >> 1;                     // 0..31
  const int n    = xcd >> 1;
  const int ho0  = ((xcd & 1) << 5) + rs;         // 0..63
  const int pxb  = ho0 << 6;
  const int co0  = coh << 7;

  // phase 0: sampling params for 64 px x 9 taps (e = tap*64 + pl)
  for (int e = tid; e < 576; e += 512) {
    const int tap = e >> 6, pl = e & 63;
    const float dy = offs[((n * 18 + 2 * tap) << 12) + pxb + pl];
    const float dx = offs[((n * 18 + 2 * tap + 1) << 12) + pxb + pl];
    const float m  = mask[((n * 9 + tap) << 12) + pxb + pl];
    const float yy = (float)(ho0 - 1 + tap / 3) + dy;
    const float xx = (float)(pl - 1 + tap % 3) + dx;
    const float y0f = floorf(yy), x0f = floorf(xx);
    const float ly = yy - y0f, lx = xx - x0f;
    const int y0 = (int)y0f, x0 = (int)x0f;
    const int y0c = min(max(y0, 0), 63);
    const int y1c = min(max(y0 + 1, 0), 63);
    const float fy0 = (y0 >= 0 && y0 < 64) ? 1.f : 0.f;
    const float fy1 = (y0 >= -1 && y0 < 63) ? 1.f : 0.f;
    const int x0c = min(max(x0, 0), 63);
    const int x1c = min(max(x0 + 1, 0), 63);
    const int bx  = min(max(x0, 0), 62);
    const float vx0 = (x0 >= 0 && x0 < 64) ? 1.f : 0.f;
    const float vx1 = (x0 >= -1 && x0 < 63) ? 1.f : 0.f;
    const float wl = (1.f - lx) * vx0 * ((x0c == bx) ? 1.f : 0.f)
                   + lx * vx1 * ((x1c == bx) ? 1.f : 0.f);
    const float wr = (1.f - lx) * vx0 * ((x0c == bx + 1) ? 1.f : 0.f)
                   + lx * vx1 * ((x1c == bx + 1) ? 1.f : 0.f);
    const float a0 = (1.f - ly) * fy0 * m;
    const float a1 = ly * fy1 * m;
    pwT[tap][pl] = make_float4(wl * a0, wr * a0, wl * a1, wr * a1);
    piT[tap][pl] = make_int2((((y0c << 6) + bx) << 2), (((y1c << 6) + bx) << 2));
  }
  __syncthreads();   // sample()/param loads read LDS written by other waves

  const int pxl = tid & 63;
  const int oct = tid >> 6;               // 0..7; also the wave id
  const char* xn = (const char*)(x + ((long)(n << 8) << 12));

  float4 pw;  // current-tap bilinear weights (registers)
  int2   pi;  // current-tap byte offsets

  auto sample = [&](int s2, int buf) {
    // channels c = 64*s2 + oct*8 + j at the current tap
    const char* p = xn + (((s2 << 6) + (oct << 3)) << 14);
    __align__(16) unsigned short v[8];
#pragma unroll
    for (int j = 0; j < 8; ++j) {
      const char* q = p + (j << 14);
      const float2_u pa = *(const float2_u*)(q + pi.x);
      const float2_u pb = *(const float2_u*)(q + pi.y);
      v[j] = f2bf(pa.x * pw.x + pa.y * pw.y + pb.x * pw.z + pb.y * pw.w);
    }
    *(int4*)&Bs[buf][pxl][oct << 3] = *(const int4*)v;
  };

  f32x4 acc[4];
#pragma unroll
  for (int nt = 0; nt < 4; ++nt)
#pragma unroll
    for (int r = 0; r < 4; ++r) acc[nt][r] = 0.f;

  pw = pwT[0][pxl];
  pi = piT[0][pxl];
  sample(0, 0);
  __syncthreads();

  const int lane = tid & 63;
  const int wv   = oct;
  const int mrow = lane & 15;
  const int koct = lane >> 4;             // 0..3 -> k-subgroup of 8
  const int arow = co0 + (wv << 4) + mrow;
  const unsigned short* wrow = wbf + arow * 2304;

  for (int ic = 0; ic < 36; ++ic) {
    const int kc = ic << 6;
    // A fragment loads (global, L2-hot) — issue before sampling
    bf16x8 af[2];
#pragma unroll
    for (int ks = 0; ks < 2; ++ks)
      af[ks] = *(const bf16x8*)(wrow + kc + (ks << 5) + (koct << 3));

    if (ic + 1 < 36) {
      if (((ic + 1) & 3) == 0) {          // tap boundary: reload params
        const int t2 = (ic + 1) >> 2;
        pw = pwT[t2][pxl];
        pi = piT[t2][pxl];
      }
      sample((ic + 1) & 3, (ic + 1) & 1);
    }

    const int buf = ic & 1;
#pragma unroll
    for (int ks = 0; ks < 2; ++ks)
#pragma unroll
      for (int nt = 0; nt < 4; ++nt) {
        const bf16x8 bfr =
            *(const bf16x8*)&Bs[buf][(nt << 4) + mrow][(ks << 5) + (koct << 3)];
        acc[nt] = __builtin_amdgcn_mfma_f32_16x16x32_bf16(af[ks], bfr,
                                                          acc[nt], 0, 0, 0);
      }
    __syncthreads();
  }

  // epilogue: C/D layout col=lane&15 (px), row=(lane>>4)*4+r (co)
#pragma unroll
  for (int nt = 0; nt < 4; ++nt)
#pragma unroll
    for (int r = 0; r < 4; ++r) {
      const int co = co0 + (wv << 4) + ((lane >> 4) << 2) + r;
      const int pxg = pxb + (nt << 4) + (lane & 15);
      out[(((n << 8) + co) << 12) + pxg] = acc[nt][r] + bias[co];
    }
}

// ---------------------------------------------------------------------------
extern "C" void kernel_launch(void* const* d_in, const int* in_sizes, int n_in,
                              void* d_out, int out_size, void* d_ws, size_t ws_size,
                              hipStream_t stream) {
  const float* x      = (const float*)d_in[0];
  const float* depth  = (const float*)d_in[1];
  const float* weight = (const float*)d_in[2];
  const float* bias   = (const float*)d_in[3];
  const float* off_w  = (const float*)d_in[4];
  const float* off_b  = (const float*)d_in[5];
  const float* mask_w = (const float*)d_in[6];
  const float* mask_b = (const float*)d_in[7];
  float* out = (float*)d_out;

  float* offs = (float*)d_ws;                       // 294912 floats
  float* mask = offs + 294912;                      // 147456 floats
  unsigned short* wbf = (unsigned short*)(mask + 147456);  // 589824 bf16

  hipMemsetAsync(offs, 0, 294912 * sizeof(float), stream);
  k_prep_weight<<<dim3(9, 256), 256, 0, stream>>>(weight, wbf);
  k_offset_conv<<<1024, 512, 0, stream>>>(x, depth, off_w, off_b, offs);
  k_mask_conv<<<256, 512, 0, stream>>>(depth, offs, mask_w, mask_b, mask);
  k_deform_gemm<<<512, 512, 0, stream>>>(x, offs, mask, wbf, bias, out);
}